// Round 12
// baseline (127.265 us; speedup 1.0000x reference)
//
#include <hip/hip_runtime.h>

#define N 8192
#define H 256
#define TOPK 16
#define NSEC 11
#define NEG_SLOPE 0.2
#define NB 256                 // K1 blocks (one per CU)
#define NT 256
#define RPB (N / NB)           // 32 rows per block
#define NSL 8                  // slices per sector in slice_topk
#define SLICE (N / NSL)        // 1024 elements per slice
#define IDX_SENT 0x7fffffff

__device__ __forceinline__ bool better(double av, int ai, double bv, int bi) {
    return (av > bv) || (av == bv && ai < bi);
}

// ---------------------------------------------------------------------------
// K1: redundant v = W^T a per block. 512 threads: phase A splits j over two
// groups (32-iteration chain instead of 64, LDS combine), phase B runs 8
// waves over the block's 32 rows (per-row numerics identical to R8-R11).
// ---------------------------------------------------------------------------
__global__ __launch_bounds__(512) void compute_v_s(
    const float* __restrict__ E, const float* __restrict__ W,
    const float* __restrict__ a,
    float* __restrict__ s1f, double* __restrict__ s2g)
{
    __shared__ float sa[2 * H];
    __shared__ double part1[2][H];
    __shared__ double part2[2][H];
    __shared__ double sv1[H];
    __shared__ double sv2[H];

    int t = threadIdx.x;   // 0..511
    int blk = blockIdx.x;
    int lane = t & 63;
    int w = t >> 6;        // wave 0..7

    sa[t] = a[t];          // 512 == 2*H
    __syncthreads();

    // ---- phase A: col = t&255, group g covers 128 j's in 4 chains ----
    {
        int col = t & 255;
        int g = t >> 8;    // 0 or 1
        double a1_0 = 0.0, a1_1 = 0.0, a1_2 = 0.0, a1_3 = 0.0;
        double a2_0 = 0.0, a2_1 = 0.0, a2_2 = 0.0, a2_3 = 0.0;
        for (int j = g * 128; j < g * 128 + 128; j += 4) {
            double w0 = (double)W[(j + 0) * H + col];
            double w1 = (double)W[(j + 1) * H + col];
            double w2 = (double)W[(j + 2) * H + col];
            double w3 = (double)W[(j + 3) * H + col];
            a1_0 += w0 * (double)sa[j + 0];
            a1_1 += w1 * (double)sa[j + 1];
            a1_2 += w2 * (double)sa[j + 2];
            a1_3 += w3 * (double)sa[j + 3];
            a2_0 += w0 * (double)sa[H + j + 0];
            a2_1 += w1 * (double)sa[H + j + 1];
            a2_2 += w2 * (double)sa[H + j + 2];
            a2_3 += w3 * (double)sa[H + j + 3];
        }
        part1[g][col] = (a1_0 + a1_1) + (a1_2 + a1_3);
        part2[g][col] = (a2_0 + a2_1) + (a2_2 + a2_3);
    }
    __syncthreads();
    if (t < H) {
        sv1[t] = part1[0][t] + part1[1][t];
        sv2[t] = part2[0][t] + part2[1][t];
    }
    __syncthreads();

    // ---- phase B: rows [blk*32, blk*32+32), wave-per-row, 8 waves ----
    for (int q = 0; q < RPB / 8; ++q) {
        int r_loc = w + 8 * q;                 // 0..31
        int row = blk * RPB + r_loc;
        const float4* Erow = (const float4*)(E + (size_t)row * H);
        float4 e = Erow[lane];
        int base = lane * 4;
        double acc1 = (double)e.x * sv1[base + 0] + (double)e.y * sv1[base + 1] +
                      (double)e.z * sv1[base + 2] + (double)e.w * sv1[base + 3];
        double acc2 = (double)e.x * sv2[base + 0] + (double)e.y * sv2[base + 1] +
                      (double)e.z * sv2[base + 2] + (double)e.w * sv2[base + 3];
        for (int o = 32; o > 0; o >>= 1) {
            acc1 += __shfl_down(acc1, o);
            acc2 += __shfl_down(acc2, o);
        }
        if (lane == 0) {
            s1f[row] = (float)acc1;
            s2g[row] = acc2;                   // f64 ordering key
        }
    }
}

// ---------------------------------------------------------------------------
// K2: 88 blocks = 11 sectors x 8 slices of 1024. Hierarchical selection with
// max 4 candidates per lane (no scratch spill). R11-proven, unchanged.
// ---------------------------------------------------------------------------
__global__ __launch_bounds__(NT) void slice_topk(
    const double* __restrict__ s2g, const int* __restrict__ sec,
    const int* __restrict__ act,
    double* __restrict__ candV, int* __restrict__ candI,
    int* __restrict__ cnts)
{
    __shared__ double wV[4][TOPK];
    __shared__ int wI[4][TOPK];
    __shared__ int wCnt[4];

    int bx = blockIdx.x;
    int c = bx >> 3;       // sector 0..10
    int sl = bx & 7;       // slice 0..7
    int t = threadIdx.x;
    int lane = t & 63;
    int w = t >> 6;

    int j0 = sl * SLICE + 4 * t;
    int4 a4 = *(const int4*)(act + j0);
    int4 s4 = *(const int4*)(sec + j0);
    double2 d01 = *(const double2*)(s2g + j0);
    double2 d23 = *(const double2*)(s2g + j0 + 2);

    bool p0 = (a4.x != 0) && (s4.x == c);
    bool p1 = (a4.y != 0) && (s4.y == c);
    bool p2 = (a4.z != 0) && (s4.z == c);
    bool p3 = (a4.w != 0) && (s4.w == c);

    double v[4];
    int ix[4];
    v[0] = p0 ? d01.x : -INFINITY;  ix[0] = p0 ? (j0 + 0) : IDX_SENT;
    v[1] = p1 ? d01.y : -INFINITY;  ix[1] = p1 ? (j0 + 1) : IDX_SENT;
    v[2] = p2 ? d23.x : -INFINITY;  ix[2] = p2 ? (j0 + 2) : IDX_SENT;
    v[3] = p3 ? d23.y : -INFINITY;  ix[3] = p3 ? (j0 + 3) : IDX_SENT;

    int cnt = __popcll(__ballot(p0)) + __popcll(__ballot(p1)) +
              __popcll(__ballot(p2)) + __popcll(__ballot(p3));

    for (int r = 0; r < TOPK; ++r) {
        double bv = v[0];
        int bi = ix[0];
#pragma unroll
        for (int p = 1; p < 4; ++p)
            if (better(v[p], ix[p], bv, bi)) { bv = v[p]; bi = ix[p]; }
        for (int o = 32; o > 0; o >>= 1) {
            double ov = __shfl_xor(bv, o);
            int oi = __shfl_xor(bi, o);
            if (better(ov, oi, bv, bi)) { bv = ov; bi = oi; }
        }
#pragma unroll
        for (int p = 0; p < 4; ++p)
            if (ix[p] == bi) { v[p] = -INFINITY; ix[p] = IDX_SENT; }
        if (lane == 0) {
            wV[w][r] = bv;
            wI[w][r] = bi;
        }
    }
    if (lane == 0) wCnt[w] = cnt;
    __syncthreads();

    if (w == 0) {
        double mv = wV[lane >> 4][lane & 15];
        int mi = wI[lane >> 4][lane & 15];
        for (int r = 0; r < TOPK; ++r) {
            double bv = mv;
            int bi = mi;
            for (int o = 32; o > 0; o >>= 1) {
                double ov = __shfl_xor(bv, o);
                int oi = __shfl_xor(bi, o);
                if (better(ov, oi, bv, bi)) { bv = ov; bi = oi; }
            }
            if (mi == bi) { mv = -INFINITY; mi = IDX_SENT; }
            if (lane == 0) {
                candV[bx * TOPK + r] = bv;
                candI[bx * TOPK + r] = bi;
            }
        }
        if (lane == 0) cnts[bx] = wCnt[0] + wCnt[1] + wCnt[2] + wCnt[3];
    }
}

// ---------------------------------------------------------------------------
// K3: fused merge + write. Each of 512 blocks redundantly merges all 11
// sectors (R10/R11-proven merge logic; ~3 sectors per wave, cand reads are
// L2-broadcast) into LDS, then writes its 16 rows (256 outputs/plane).
// ---------------------------------------------------------------------------
__global__ __launch_bounds__(NT) void merge_write(
    const float* __restrict__ s1f, const double* __restrict__ s2g,
    const int* __restrict__ sec, const int* __restrict__ act,
    const double* __restrict__ candV, const int* __restrict__ candI,
    const int* __restrict__ cnts,
    float* __restrict__ out)
{
    __shared__ int sTop[NSEC][TOPK];
    __shared__ int sFill[NSEC][TOPK];
    __shared__ int sM[NSEC];

    int t = threadIdx.x;
    int lane = t & 63;
    int w = t >> 6;  // 0..3

    for (int c = w; c < NSEC; c += 4) {
        const double* cbV = candV + (size_t)c * NSL * TOPK;   // 128 entries
        const int* cbI = candI + (size_t)c * NSL * TOPK;
        double v0 = cbV[lane];
        int i0 = cbI[lane];
        double v1 = cbV[lane + 64];
        int i1 = cbI[lane + 64];

        for (int r = 0; r < TOPK; ++r) {
            double bv;
            int bi;
            if (better(v0, i0, v1, i1)) { bv = v0; bi = i0; }
            else                        { bv = v1; bi = i1; }
            for (int o = 32; o > 0; o >>= 1) {
                double ov = __shfl_xor(bv, o);
                int oi = __shfl_xor(bi, o);
                if (better(ov, oi, bv, bi)) { bv = ov; bi = oi; }
            }
            if (i0 == bi)      { v0 = -INFINITY; i0 = IDX_SENT; }
            else if (i1 == bi) { v1 = -INFINITY; i1 = IDX_SENT; }
            if (lane == 0) sTop[c][r] = (bi == IDX_SENT) ? -1 : bi;
        }

        // m = min(16, total active in sector)
        int cl = (lane < NSL) ? cnts[c * NSL + lane] : 0;
        for (int o = 32; o > 0; o >>= 1) cl += __shfl_xor(cl, o);
        if (lane == 0) sM[c] = (cl < TOPK) ? cl : TOPK;

        // fill indices: first 16 j failing the predicate
        int cnt2 = 0;
        for (int basej = 0; basej < N && cnt2 < TOPK; basej += 64) {
            int j = basej + lane;
            bool fail = !((act[j] != 0) && (sec[j] == c));
            unsigned long long mask = __ballot(fail);
            if (fail) {
                int rank = cnt2 + __popcll(mask & ((1ull << lane) - 1));
                if (rank < TOPK) sFill[c][rank] = j;
            }
            cnt2 += __popcll(mask);
        }
    }
    __syncthreads();

    // write this block's 256 outputs per plane (16 rows)
    int gid = blockIdx.x * NT + t;  // N*TOPK total
    int i = gid >> 4;
    int slot = gid & 15;

    float wgt = 0.0f;
    float fidx;
    float fvalid = 0.0f;

    if (act[i] == 0) {
        fidx = (float)slot;  // all -inf row: stable top_k -> indices 0..15
    } else {
        int c = sec[i];
        int m = sM[c];
        if (slot < m) {
            int j = sTop[c][slot];
            double x = (double)s1f[i] + s2g[j];
            double attv = (x >= 0.0) ? x : NEG_SLOPE * x;
            wgt = (float)attv;
            fvalid = 1.0f;
            fidx = (float)j;
        } else {
            fidx = (float)sFill[c][slot - m];
        }
    }

    out[gid] = wgt;
    out[N * TOPK + gid] = fidx;
    out[2 * N * TOPK + gid] = fvalid;
}

extern "C" void kernel_launch(void* const* d_in, const int* in_sizes, int n_in,
                              void* d_out, int out_size, void* d_ws, size_t ws_size,
                              hipStream_t stream) {
    const float* E = (const float*)d_in[0];
    const float* W = (const float*)d_in[1];
    const float* a = (const float*)d_in[2];
    const int* sec = (const int*)d_in[3];
    const int* act = (const int*)d_in[4];  // bool input uploaded as int32

    // workspace (~115 KB, 8-byte aligned first) — proven range
    char* ws = (char*)d_ws;
    double* s2g = (double*)ws;                     // N f64
    double* candV = s2g + N;                       // NSEC*NSL*TOPK = 1408 f64
    float* s1f = (float*)(candV + NSEC * NSL * TOPK);  // N f32
    int* candI = (int*)(s1f + N);                  // 1408 i32
    int* cnts = candI + NSEC * NSL * TOPK;         // NSEC*NSL = 88
    float* out = (float*)d_out;

    hipLaunchKernelGGL(compute_v_s, dim3(NB), dim3(512), 0, stream,
                       E, W, a, s1f, s2g);
    hipLaunchKernelGGL(slice_topk, dim3(NSEC * NSL), dim3(NT), 0, stream,
                       s2g, sec, act, candV, candI, cnts);
    hipLaunchKernelGGL(merge_write, dim3((N * TOPK) / NT), dim3(NT), 0, stream,
                       s1f, s2g, sec, act, candV, candI, cnts, out);
}

// Round 13
// 111.279 us; speedup vs baseline: 1.1437x; 1.1437x over previous
//
#include <hip/hip_runtime.h>

#define N 8192
#define H 256
#define TOPK 16
#define NSEC 11
#define NEG_SLOPE 0.2
#define NB 256                 // K1 blocks (one per CU)
#define NT 256                 // threads per block
#define RPB (N / NB)           // 32 rows per block
#define NSL 8                  // slices per sector in slice_topk
#define SLICE (N / NSL)        // 1024 elements per slice
#define IDX_SENT 0x7fffffff

__device__ __forceinline__ bool better(double av, int ai, double bv, int bi) {
    return (av > bv) || (av == bv && ai < bi);
}

// ---------------------------------------------------------------------------
// K1: redundant v = W^T a per block (4 independent f64 chains, R8-R11 proven),
// then s1/s2 for the block's 32 rows. CHANGE vs R11: phase B issues all 8
// row-loads per wave up front (one latency round instead of 8) and hoists
// sv1/sv2 LDS reads to registers. Per-row numerics identical.
// ---------------------------------------------------------------------------
__global__ __launch_bounds__(NT) void compute_v_s(
    const float* __restrict__ E, const float* __restrict__ W,
    const float* __restrict__ a,
    float* __restrict__ s1f, double* __restrict__ s2g)
{
    __shared__ float sa[2 * H];
    __shared__ double sv1[H];
    __shared__ double sv2[H];

    int t = threadIdx.x;
    int blk = blockIdx.x;
    int lane = t & 63;
    int w = t >> 6;  // wave 0..3

    sa[t] = a[t];
    sa[t + H] = a[t + H];
    __syncthreads();

    // ---- phase A: thread t owns column t; 4 independent chains ----
    {
        double a1_0 = 0.0, a1_1 = 0.0, a1_2 = 0.0, a1_3 = 0.0;
        double a2_0 = 0.0, a2_1 = 0.0, a2_2 = 0.0, a2_3 = 0.0;
        for (int j = 0; j < H; j += 4) {
            double w0 = (double)W[(j + 0) * H + t];
            double w1 = (double)W[(j + 1) * H + t];
            double w2 = (double)W[(j + 2) * H + t];
            double w3 = (double)W[(j + 3) * H + t];
            a1_0 += w0 * (double)sa[j + 0];
            a1_1 += w1 * (double)sa[j + 1];
            a1_2 += w2 * (double)sa[j + 2];
            a1_3 += w3 * (double)sa[j + 3];
            a2_0 += w0 * (double)sa[H + j + 0];
            a2_1 += w1 * (double)sa[H + j + 1];
            a2_2 += w2 * (double)sa[H + j + 2];
            a2_3 += w3 * (double)sa[H + j + 3];
        }
        sv1[t] = (a1_0 + a1_1) + (a1_2 + a1_3);
        sv2[t] = (a2_0 + a2_1) + (a2_2 + a2_3);
    }
    __syncthreads();

    // ---- phase B: rows [blk*32 .. +32), wave-per-row, loads batched ----
    {
        float4 e[RPB / 4];                       // 8 row fragments, independent
#pragma unroll
        for (int q = 0; q < RPB / 4; ++q) {
            int row = blk * RPB + (w + 4 * q);
            e[q] = ((const float4*)(E + (size_t)row * H))[lane];
        }
        int base = lane * 4;
        double b10 = sv1[base + 0], b11 = sv1[base + 1],
               b12 = sv1[base + 2], b13 = sv1[base + 3];
        double b20 = sv2[base + 0], b21 = sv2[base + 1],
               b22 = sv2[base + 2], b23 = sv2[base + 3];
#pragma unroll
        for (int q = 0; q < RPB / 4; ++q) {
            int row = blk * RPB + (w + 4 * q);
            double acc1 = (double)e[q].x * b10 + (double)e[q].y * b11 +
                          (double)e[q].z * b12 + (double)e[q].w * b13;
            double acc2 = (double)e[q].x * b20 + (double)e[q].y * b21 +
                          (double)e[q].z * b22 + (double)e[q].w * b23;
            for (int o = 32; o > 0; o >>= 1) {
                acc1 += __shfl_down(acc1, o);
                acc2 += __shfl_down(acc2, o);
            }
            if (lane == 0) {
                s1f[row] = (float)acc1;
                s2g[row] = acc2;               // f64 ordering key
            }
        }
    }
}

// ---------------------------------------------------------------------------
// K2: 88 blocks = 11 sectors x 8 slices of 1024. Hierarchical selection with
// max 4 candidates per lane (no scratch spill). R11-proven, unchanged.
// ---------------------------------------------------------------------------
__global__ __launch_bounds__(NT) void slice_topk(
    const double* __restrict__ s2g, const int* __restrict__ sec,
    const int* __restrict__ act,
    double* __restrict__ candV, int* __restrict__ candI,
    int* __restrict__ cnts)
{
    __shared__ double wV[4][TOPK];
    __shared__ int wI[4][TOPK];
    __shared__ int wCnt[4];

    int bx = blockIdx.x;
    int c = bx >> 3;       // sector 0..10
    int sl = bx & 7;       // slice 0..7
    int t = threadIdx.x;
    int lane = t & 63;
    int w = t >> 6;

    int j0 = sl * SLICE + 4 * t;
    int4 a4 = *(const int4*)(act + j0);
    int4 s4 = *(const int4*)(sec + j0);
    double2 d01 = *(const double2*)(s2g + j0);
    double2 d23 = *(const double2*)(s2g + j0 + 2);

    bool p0 = (a4.x != 0) && (s4.x == c);
    bool p1 = (a4.y != 0) && (s4.y == c);
    bool p2 = (a4.z != 0) && (s4.z == c);
    bool p3 = (a4.w != 0) && (s4.w == c);

    double v[4];
    int ix[4];
    v[0] = p0 ? d01.x : -INFINITY;  ix[0] = p0 ? (j0 + 0) : IDX_SENT;
    v[1] = p1 ? d01.y : -INFINITY;  ix[1] = p1 ? (j0 + 1) : IDX_SENT;
    v[2] = p2 ? d23.x : -INFINITY;  ix[2] = p2 ? (j0 + 2) : IDX_SENT;
    v[3] = p3 ? d23.y : -INFINITY;  ix[3] = p3 ? (j0 + 3) : IDX_SENT;

    int cnt = __popcll(__ballot(p0)) + __popcll(__ballot(p1)) +
              __popcll(__ballot(p2)) + __popcll(__ballot(p3));

    for (int r = 0; r < TOPK; ++r) {
        double bv = v[0];
        int bi = ix[0];
#pragma unroll
        for (int p = 1; p < 4; ++p)
            if (better(v[p], ix[p], bv, bi)) { bv = v[p]; bi = ix[p]; }
        for (int o = 32; o > 0; o >>= 1) {
            double ov = __shfl_xor(bv, o);
            int oi = __shfl_xor(bi, o);
            if (better(ov, oi, bv, bi)) { bv = ov; bi = oi; }
        }
#pragma unroll
        for (int p = 0; p < 4; ++p)
            if (ix[p] == bi) { v[p] = -INFINITY; ix[p] = IDX_SENT; }
        if (lane == 0) {
            wV[w][r] = bv;
            wI[w][r] = bi;
        }
    }
    if (lane == 0) wCnt[w] = cnt;
    __syncthreads();

    if (w == 0) {
        double mv = wV[lane >> 4][lane & 15];
        int mi = wI[lane >> 4][lane & 15];
        for (int r = 0; r < TOPK; ++r) {
            double bv = mv;
            int bi = mi;
            for (int o = 32; o > 0; o >>= 1) {
                double ov = __shfl_xor(bv, o);
                int oi = __shfl_xor(bi, o);
                if (better(ov, oi, bv, bi)) { bv = ov; bi = oi; }
            }
            if (mi == bi) { mv = -INFINITY; mi = IDX_SENT; }
            if (lane == 0) {
                candV[bx * TOPK + r] = bv;
                candI[bx * TOPK + r] = bi;
            }
        }
        if (lane == 0) cnts[bx] = wCnt[0] + wCnt[1] + wCnt[2] + wCnt[3];
    }
}

// ---------------------------------------------------------------------------
// K3: one wave per sector. Merge 8 sorted 16-lists (= 128 candidates, 2 per
// lane) by 16 argmax rounds with remove-by-index. Also m and fill indices.
// R10/R11-proven, unchanged.
// ---------------------------------------------------------------------------
__global__ __launch_bounds__(64) void merge_topk(
    const double* __restrict__ candV, const int* __restrict__ candI,
    const int* __restrict__ cnts, const int* __restrict__ sec,
    const int* __restrict__ act,
    int* __restrict__ top_idx, int* __restrict__ fill_idx,
    int* __restrict__ m_arr)
{
    int c = blockIdx.x;
    int lane = threadIdx.x;

    const double* cbV = candV + (size_t)c * NSL * TOPK;   // 128 entries
    const int* cbI = candI + (size_t)c * NSL * TOPK;
    double v0 = cbV[lane];
    int i0 = cbI[lane];
    double v1 = cbV[lane + 64];
    int i1 = cbI[lane + 64];

    for (int r = 0; r < TOPK; ++r) {
        double bv;
        int bi;
        if (better(v0, i0, v1, i1)) { bv = v0; bi = i0; }
        else                        { bv = v1; bi = i1; }
        for (int o = 32; o > 0; o >>= 1) {
            double ov = __shfl_xor(bv, o);
            int oi = __shfl_xor(bi, o);
            if (better(ov, oi, bv, bi)) { bv = ov; bi = oi; }
        }
        if (i0 == bi)      { v0 = -INFINITY; i0 = IDX_SENT; }
        else if (i1 == bi) { v1 = -INFINITY; i1 = IDX_SENT; }
        if (lane == 0) top_idx[c * TOPK + r] = (bi == IDX_SENT) ? -1 : bi;
    }

    // m = min(16, total active in sector)
    int cl = (lane < NSL) ? cnts[c * NSL + lane] : 0;
    for (int o = 32; o > 0; o >>= 1) cl += __shfl_xor(cl, o);
    if (lane == 0) m_arr[c] = (cl < TOPK) ? cl : TOPK;

    // fill indices: first 16 j failing the predicate (usually 1 iteration)
    int cnt2 = 0;
    for (int basej = 0; basej < N && cnt2 < TOPK; basej += 64) {
        int j = basej + lane;
        bool fail = !((act[j] != 0) && (sec[j] == c));
        unsigned long long mask = __ballot(fail);
        if (fail) {
            int rank = cnt2 + __popcll(mask & ((1ull << lane) - 1));
            if (rank < TOPK) fill_idx[c * TOPK + rank] = j;
        }
        cnt2 += __popcll(mask);
    }
}

// ---------------------------------------------------------------------------
// K4: write outputs (weight, index-as-float, valid-as-float planes).
// R11-proven, unchanged.
// ---------------------------------------------------------------------------
__global__ __launch_bounds__(NT) void write_out(const float* __restrict__ s1f,
                                                const double* __restrict__ s2g,
                                                const int* __restrict__ sec,
                                                const int* __restrict__ act,
                                                const int* __restrict__ top_idx,
                                                const int* __restrict__ fill_idx,
                                                const int* __restrict__ m_arr,
                                                float* __restrict__ out) {
    int gid = blockIdx.x * NT + threadIdx.x;  // N*TOPK total
    int i = gid >> 4;
    int slot = gid & 15;

    float wgt = 0.0f;
    float fidx;
    float fvalid = 0.0f;

    if (act[i] == 0) {
        fidx = (float)slot;  // all -inf row: stable top_k -> indices 0..15
    } else {
        int c = sec[i];
        int m = m_arr[c];
        if (slot < m) {
            int j = top_idx[c * TOPK + slot];
            double x = (double)s1f[i] + s2g[j];
            double attv = (x >= 0.0) ? x : NEG_SLOPE * x;
            wgt = (float)attv;
            fvalid = 1.0f;
            fidx = (float)j;
        } else {
            fidx = (float)fill_idx[c * TOPK + (slot - m)];
        }
    }

    out[gid] = wgt;
    out[N * TOPK + gid] = fidx;
    out[2 * N * TOPK + gid] = fvalid;
}

extern "C" void kernel_launch(void* const* d_in, const int* in_sizes, int n_in,
                              void* d_out, int out_size, void* d_ws, size_t ws_size,
                              hipStream_t stream) {
    const float* E = (const float*)d_in[0];
    const float* W = (const float*)d_in[1];
    const float* a = (const float*)d_in[2];
    const int* sec = (const int*)d_in[3];
    const int* act = (const int*)d_in[4];  // bool input uploaded as int32

    // workspace (~115 KB, 8-byte aligned first) — proven range
    char* ws = (char*)d_ws;
    double* s2g = (double*)ws;                     // N f64
    double* candV = s2g + N;                       // NSEC*NSL*TOPK = 1408 f64
    float* s1f = (float*)(candV + NSEC * NSL * TOPK);  // N f32
    int* candI = (int*)(s1f + N);                  // 1408 i32
    int* cnts = candI + NSEC * NSL * TOPK;         // NSEC*NSL = 88
    int* top_idx = cnts + NSEC * NSL;              // NSEC*TOPK
    int* fill_idx = top_idx + NSEC * TOPK;         // NSEC*TOPK
    int* m_arr = fill_idx + NSEC * TOPK;           // NSEC

    float* out = (float*)d_out;

    hipLaunchKernelGGL(compute_v_s, dim3(NB), dim3(NT), 0, stream,
                       E, W, a, s1f, s2g);
    hipLaunchKernelGGL(slice_topk, dim3(NSEC * NSL), dim3(NT), 0, stream,
                       s2g, sec, act, candV, candI, cnts);
    hipLaunchKernelGGL(merge_topk, dim3(NSEC), dim3(64), 0, stream,
                       candV, candI, cnts, sec, act, top_idx, fill_idx, m_arr);
    hipLaunchKernelGGL(write_out, dim3((N * TOPK) / NT), dim3(NT), 0, stream,
                       s1f, s2g, sec, act, top_idx, fill_idx, m_arr, out);
}